// Round 5
// baseline (683.096 us; speedup 1.0000x reference)
//
#include <hip/hip_runtime.h>
#include <hip/hip_bf16.h>

// MultimodalFusion: B=16384, S=3, D=512, H=8, HD=64, FF=2048
// Round 5: GEMM tile 128x256, 8 waves (512 thr), wave grid 2x4, each wave
// 4x4 of 16x16x32 MFMA (64-VGPR acc, same as proven round-2/4 wave shape).
// Compute:staging ratio per barrier 85 vs 64 (1.33x); LDS 48 KB -> 3 blk/CU.
// Staging/swizzle mechanics identical to round-2 (0-conflict proven).
// Pipeline (nch=1, 9 dispatches, all intermediates bf16, in-place aliasing):
//   K0 cast all weights fp32->bf16 (arena)
//   K1 x = feat+pos -> bf16                 xbf [rows,512]
//   K2 GEMM qkv = x@w_in^T+b_in -> bf16     regB stride 1536
//   K3 attention in-place: o over q-slice
//   K4 GEMM y' = x + o@w_out^T+b_out        regB+512 (over k-slice)
//   K5 x1 = LN1(y') -> bf16                 xbf
//   K6 GEMM h = relu(x1@w1^T+b1)            regB stride 2048
//   K7 GEMM f' = x1 + h@w2^T+b2             xbf in-place
//   K8 out[b] = mean_s LN2(f')

#define BTOT 16384
#define DD 512
#define EPS_ 1e-5f

typedef __attribute__((ext_vector_type(8))) short bf8v;
typedef __attribute__((ext_vector_type(4))) float f4v;

__device__ __forceinline__ unsigned short f2bf(float f) {
  unsigned int u = __builtin_bit_cast(unsigned int, f);
  u += 0x7fffu + ((u >> 16) & 1u);
  return (unsigned short)(u >> 16);
}
__device__ __forceinline__ float bf2f(unsigned short s) {
  unsigned int u = ((unsigned int)s) << 16;
  return __builtin_bit_cast(float, u);
}
__device__ __forceinline__ unsigned int pk2(float a, float b) {
  return (unsigned int)f2bf(a) | ((unsigned int)f2bf(b) << 16);
}
__device__ __forceinline__ void unpk8(uint4 raw, float* x) {
  x[0] = bf2f(raw.x & 0xffff); x[1] = bf2f(raw.x >> 16);
  x[2] = bf2f(raw.y & 0xffff); x[3] = bf2f(raw.y >> 16);
  x[4] = bf2f(raw.z & 0xffff); x[5] = bf2f(raw.z >> 16);
  x[6] = bf2f(raw.w & 0xffff); x[7] = bf2f(raw.w >> 16);
}

// async global->LDS, 16B per lane; lds dst is wave-uniform base + lane*16
#define GLDS16(gp, lp)                                                   \
  __builtin_amdgcn_global_load_lds(                                      \
      (const __attribute__((address_space(1))) void*)(gp),               \
      (__attribute__((address_space(3))) void*)(lp), 16, 0, 0)

// ---------------- K0: fused weight cast into contiguous bf16 arena --------
__global__ __launch_bounds__(256) void cast_all(const float* __restrict__ wi,
                                                const float* __restrict__ wo,
                                                const float* __restrict__ w1,
                                                const float* __restrict__ w2,
                                                unsigned short* __restrict__ arena) {
  int i = (blockIdx.x * 256 + threadIdx.x) * 4;
  const float* src; int off;
  if (i < 786432)       { src = wi; off = 0; }
  else if (i < 1048576) { src = wo; off = 786432; }
  else if (i < 2097152) { src = w1; off = 1048576; }
  else                  { src = w2; off = 2097152; }
  float4 v = *(const float4*)&src[i - off];
  uint2 u; u.x = pk2(v.x, v.y); u.y = pk2(v.z, v.w);
  *(uint2*)&arena[i] = u;
}

// ---------------- K1: build x = feat + pos -> bf16 ----------------
__global__ __launch_bounds__(256) void build_x(const float* __restrict__ f0,
                                               const float* __restrict__ f1,
                                               const float* __restrict__ f2,
                                               const float* __restrict__ pos,
                                               unsigned short* __restrict__ xbf, int b0) {
  int gi = blockIdx.x * 256 + threadIdx.x;
  int e = gi * 4;
  int r = e >> 9;
  int d = e & 511;
  int bl = r / 3, s = r - bl * 3;
  const float* f = (s == 0 ? f0 : (s == 1 ? f1 : f2)) + (size_t)(b0 + bl) * DD + d;
  const float* pp = pos + s * DD + d;
  float4 fv = *(const float4*)f;
  float4 pv = *(const float4*)pp;
  uint2 o; o.x = pk2(fv.x + pv.x, fv.y + pv.y); o.y = pk2(fv.z + pv.z, fv.w + pv.w);
  *(uint2*)&xbf[(size_t)r * DD + d] = o;
}

// ---------------- GEMM: C[M,N] = A[M,K] @ Bw[N,K]^T + bias (+res) ---------
// TM=128, TN=256, 8 waves in 2x4, wave = 4x4 of 16x16x32 MFMA, BK=64.
// Staging chunk = 8 tile-rows x 64 k (1 KiB, one wave-GLDS): lane l -> row
// chunk*8 + (l>>3), k-chunk (l&7)^(l>>3) (XOR swizzle on global side; LDS
// dst lane-ordered). A: 16 chunks, B: 32 chunks; wave w stages A[w*2..+2),
// B[w*4..+4). Fragment read slot = (((kk>>3)+ql)^(row&7))*8 — 0 conflicts
// (round-2 proven). XCD-aware block swizzle (RT % 8 == 0).
template <int ACT, int RES>
__global__ __launch_bounds__(512, 2) void gemm_bt(const unsigned short* __restrict__ A,
                                                  int lda,
                                                  const unsigned short* __restrict__ Bw,
                                                  const float* __restrict__ bias,
                                                  const unsigned short* res,
                                                  unsigned short* C, int ldc,
                                                  int N, int K) {
  __shared__ unsigned short lA[128 * 64];
  __shared__ unsigned short lB[256 * 64];
  const int tid = threadIdx.x;
  const int gx = gridDim.x;
  const int bid = blockIdx.y * gx + blockIdx.x;
  const int xcd = bid & 7;
  const int ii = bid >> 3;
  const int row0 = (xcd + 8 * (ii / gx)) * 128;
  const int col0 = (ii % gx) * 256;

  const int lane = tid & 63;
  const int w = tid >> 6;              // 0..7
  const int wm = (w >> 2) * 64;        // 2 wave-rows
  const int wn = (w & 3) * 64;         // 4 wave-cols
  const int lr = lane & 15;
  const int ql = lane >> 4;
  const int xk = lr & 7;

  f4v acc[4][4];
#pragma unroll
  for (int i = 0; i < 4; i++)
#pragma unroll
    for (int j = 0; j < 4; j++) acc[i][j] = (f4v)0.f;

  // staging geometry
  const int srow = lane >> 3;                 // 0..7
  const int sq = (lane & 7) ^ srow;           // swizzled k-chunk
  const int c0a = w * 2;                      // A chunks [c0a, c0a+2)
  const int c0b = w * 4;                      // B chunks [c0b, c0b+4)
  const unsigned short* Ag0 = A + (size_t)(row0 + c0a * 8 + srow) * lda + sq * 8;
  const unsigned short* Bg0 = Bw + (size_t)(col0 + c0b * 8 + srow) * K + sq * 8;
  unsigned short* lA0 = &lA[c0a * 512];
  unsigned short* lB0 = &lB[c0b * 512];

  for (int k0 = 0; k0 < K; k0 += 64) {
#pragma unroll
    for (int i = 0; i < 2; i++)
      GLDS16(Ag0 + (size_t)(i * 8) * lda + k0, lA0 + i * 512);
#pragma unroll
    for (int i = 0; i < 4; i++)
      GLDS16(Bg0 + (size_t)(i * 8) * K + k0, lB0 + i * 512);
    __syncthreads();
#pragma unroll
    for (int kk = 0; kk < 64; kk += 32) {
      const int slot = (((kk >> 3) + ql) ^ xk) * 8;
      bf8v af[4], bfr[4];
#pragma unroll
      for (int i = 0; i < 4; i++)
        af[i] = *(const bf8v*)&lA[(wm + i * 16 + lr) * 64 + slot];
#pragma unroll
      for (int j = 0; j < 4; j++)
        bfr[j] = *(const bf8v*)&lB[(wn + j * 16 + lr) * 64 + slot];
#pragma unroll
      for (int i = 0; i < 4; i++)
#pragma unroll
        for (int j = 0; j < 4; j++)
          acc[i][j] = __builtin_amdgcn_mfma_f32_16x16x32_bf16(af[i], bfr[j], acc[i][j], 0, 0, 0);
    }
    __syncthreads();
  }

#pragma unroll
  for (int j = 0; j < 4; j++) {
    int gcol = col0 + wn + j * 16 + lr;
    float bv = bias[gcol];
#pragma unroll
    for (int i = 0; i < 4; i++) {
#pragma unroll
      for (int r = 0; r < 4; r++) {
        int grow = row0 + wm + i * 16 + ql * 4 + r;
        float v = acc[i][j][r] + bv;
        if (RES) v += bf2f(res[(size_t)grow * N + gcol]);
        if (ACT) v = fmaxf(v, 0.f);
        C[(size_t)grow * ldc + gcol] = f2bf(v);
      }
    }
  }
}

// ---------------- K3: attention, IN-PLACE o over q-slice ----------------
__global__ __launch_bounds__(512) void attn_k(unsigned short* __restrict__ qkv) {
  int b = blockIdx.x;
  int h = threadIdx.x >> 6;
  int lane = threadIdx.x & 63;
  size_t base = ((size_t)b * 3) * 1536 + h * 64 + lane;
  float q[3], k[3], v[3];
#pragma unroll
  for (int s = 0; s < 3; s++) {
    q[s] = bf2f(qkv[base + (size_t)s * 1536]);
    k[s] = bf2f(qkv[base + (size_t)s * 1536 + 512]);
    v[s] = bf2f(qkv[base + (size_t)s * 1536 + 1024]);
  }
  float sc[3][3];
#pragma unroll
  for (int qi = 0; qi < 3; qi++)
#pragma unroll
    for (int ki = 0; ki < 3; ki++) {
      float p = q[qi] * k[ki];
#pragma unroll
      for (int off = 32; off > 0; off >>= 1) p += __shfl_xor(p, off, 64);
      sc[qi][ki] = p * 0.125f;  // 1/sqrt(64)
    }
#pragma unroll
  for (int qi = 0; qi < 3; qi++) {
    float m = fmaxf(sc[qi][0], fmaxf(sc[qi][1], sc[qi][2]));
    float e0 = __expf(sc[qi][0] - m), e1 = __expf(sc[qi][1] - m), e2 = __expf(sc[qi][2] - m);
    float inv = 1.f / (e0 + e1 + e2);
    float o = (e0 * v[0] + e1 * v[1] + e2 * v[2]) * inv;
    qkv[base + (size_t)qi * 1536] = f2bf(o);  // o over q
  }
}

// ---------------- K5: x1 = LN(y') -> bf16; one wave per row ----------------
__global__ __launch_bounds__(256) void ln_row(const unsigned short* __restrict__ y,
                                              int ldy,
                                              const float* __restrict__ g,
                                              const float* __restrict__ be,
                                              unsigned short* __restrict__ xo) {
  int wid = threadIdx.x >> 6, lane = threadIdx.x & 63;
  size_t r = (size_t)blockIdx.x * 4 + wid;
  int d = lane * 8;
  float x[8];
  unpk8(*(const uint4*)&y[r * ldy + d], x);
  float su = 0.f, sq = 0.f;
#pragma unroll
  for (int i = 0; i < 8; i++) { su += x[i]; sq += x[i] * x[i]; }
#pragma unroll
  for (int off = 32; off > 0; off >>= 1) {
    su += __shfl_xor(su, off, 64);
    sq += __shfl_xor(sq, off, 64);
  }
  float mean = su * (1.f / 512.f);
  float var = sq * (1.f / 512.f) - mean * mean;
  float rs = rsqrtf(var + EPS_);
  unsigned short o[8];
#pragma unroll
  for (int i = 0; i < 8; i++) o[i] = f2bf((x[i] - mean) * rs * g[d + i] + be[d + i]);
  uint4 pack;
  pack.x = (unsigned)o[0] | ((unsigned)o[1] << 16);
  pack.y = (unsigned)o[2] | ((unsigned)o[3] << 16);
  pack.z = (unsigned)o[4] | ((unsigned)o[5] << 16);
  pack.w = (unsigned)o[6] | ((unsigned)o[7] << 16);
  *(uint4*)&xo[r * DD + d] = pack;
}

// ---------------- K8: out[b] = mean_s LN2(f') ----------------
__global__ __launch_bounds__(192) void final_k(const unsigned short* __restrict__ ff,
                                               const float* __restrict__ g,
                                               const float* __restrict__ be,
                                               float* __restrict__ out) {
  __shared__ float t3[3][DD];
  int w = threadIdx.x >> 6, lane = threadIdx.x & 63;
  int b = blockIdx.x;
  size_t r = (size_t)b * 3 + w;
  int d = lane * 8;
  float x[8];
  unpk8(*(const uint4*)&ff[r * DD + d], x);
  float su = 0.f, sq = 0.f;
#pragma unroll
  for (int i = 0; i < 8; i++) { su += x[i]; sq += x[i] * x[i]; }
#pragma unroll
  for (int off = 32; off > 0; off >>= 1) {
    su += __shfl_xor(su, off, 64);
    sq += __shfl_xor(sq, off, 64);
  }
  float mean = su * (1.f / 512.f);
  float var = sq * (1.f / 512.f) - mean * mean;
  float rs = rsqrtf(var + EPS_);
#pragma unroll
  for (int i = 0; i < 8; i++) t3[w][d + i] = (x[i] - mean) * rs * g[d + i] + be[d + i];
  __syncthreads();
  for (int dd = threadIdx.x; dd < DD; dd += 192)
    out[(size_t)b * DD + dd] = (t3[0][dd] + t3[1][dd] + t3[2][dd]) * (1.f / 3.f);
}

extern "C" void kernel_launch(void* const* d_in, const int* in_sizes, int n_in,
                              void* d_out, int out_size, void* d_ws, size_t ws_size,
                              hipStream_t stream) {
  const float* feat0 = (const float*)d_in[0];
  const float* feat1 = (const float*)d_in[1];
  const float* feat2 = (const float*)d_in[2];
  const float* pos   = (const float*)d_in[3];
  const float* w_in  = (const float*)d_in[4];
  const float* b_in  = (const float*)d_in[5];
  const float* w_out = (const float*)d_in[6];
  const float* b_out = (const float*)d_in[7];
  const float* ln1_g = (const float*)d_in[8];
  const float* ln1_b = (const float*)d_in[9];
  const float* w1    = (const float*)d_in[10];
  const float* b1    = (const float*)d_in[11];
  const float* w2    = (const float*)d_in[12];
  const float* b2    = (const float*)d_in[13];
  const float* ln2_g = (const float*)d_in[14];
  const float* ln2_b = (const float*)d_in[15];
  float* out = (float*)d_out;

  // ---- workspace carve: weight arena + per-row 5120 B ----
  unsigned short* arena  = (unsigned short*)d_ws;
  unsigned short* w_in_b  = arena;
  unsigned short* w_out_b = arena + 786432;
  unsigned short* w1_b    = arena + 1048576;
  unsigned short* w2_b    = arena + 2097152;
  char* p = (char*)d_ws + (size_t)3145728 * 2;
  const size_t wbytes = (size_t)3145728 * 2;

  int nch = 16;
  for (int c = 1; c <= 16; c <<= 1) {
    size_t rws = (size_t)(BTOT / c) * 3;
    if (wbytes + rws * 5120 <= ws_size) { nch = c; break; }
  }
  const int Bc = BTOT / nch;
  const int rows = Bc * 3;
  const int RT = rows / 128;

  unsigned short* xbf = (unsigned short*)p;                 // x -> x1 -> f'
  unsigned short* regB = xbf + (size_t)rows * 512;          // qkv/o/y' (1536) -> h (2048)

  cast_all<<<3072, 256, 0, stream>>>(w_in, w_out, w1, w2, arena);

  for (int c = 0; c < nch; c++) {
    int b0 = c * Bc;
    build_x<<<rows / 2, 256, 0, stream>>>(feat0, feat1, feat2, pos, xbf, b0);
    gemm_bt<0, 0><<<dim3(6, RT), 512, 0, stream>>>(
        xbf, 512, w_in_b, b_in, nullptr, regB, 1536, 1536, 512);
    attn_k<<<Bc, 512, 0, stream>>>(regB);
    gemm_bt<0, 1><<<dim3(2, RT), 512, 0, stream>>>(
        regB, 1536, w_out_b, b_out, xbf, regB + 512, 1536, 512, 512);  // y'
    ln_row<<<rows / 4, 256, 0, stream>>>(regB + 512, 1536, ln1_g, ln1_b, xbf);
    gemm_bt<1, 0><<<dim3(8, RT), 512, 0, stream>>>(
        xbf, 512, w1_b, b1, nullptr, regB, 2048, 2048, 512);           // h
    gemm_bt<0, 1><<<dim3(2, RT), 512, 0, stream>>>(
        regB, 2048, w2_b, b2, xbf, xbf, 512, 512, 2048);               // f' in-place
    final_k<<<Bc, 192, 0, stream>>>(xbf, ln2_g, ln2_b, out + (size_t)b0 * DD);
  }
}